// Round 3
// baseline (258.097 us; speedup 1.0000x reference)
//
#include <hip/hip_runtime.h>
#include <hip/hip_bf16.h>

// Problem constants (T, B, H, D_MODEL) = (4096, 16, 256, 256)
#define T_LEN 4096
#define BATCH 16
#define NH    256
#define DM    256
#define M_TOT (T_LEN * BATCH)   // 65536 rows for both GEMMs

typedef __hip_bfloat16 bf16;
typedef __attribute__((ext_vector_type(8))) short bf16x8;  // 8 bf16 = 4 VGPRs
typedef __attribute__((ext_vector_type(4))) float f32x4;

// manual RTNE f32->bf16 (bit-level)
__device__ __forceinline__ unsigned short f2bf_bits(float f) {
    unsigned int u = __float_as_uint(f);
    return (unsigned short)((u + 0x7fffu + ((u >> 16) & 1u)) >> 16);
}

// async global->LDS, 16 B per lane. LDS dest must be wave-uniform base;
// HW scatters lane i to base + i*16 (m97/m104 contract -> LDS stays linear;
// swizzled layouts are achieved by pre-swizzling the GLOBAL source, m173).
typedef const unsigned int __attribute__((address_space(1)))* gas_ptr;
typedef unsigned int __attribute__((address_space(3)))* las_ptr;
__device__ __forceinline__ void async16(const bf16* g, bf16* l) {
    __builtin_amdgcn_global_load_lds((gas_ptr)g, (las_ptr)l, 16, 0, 0);
}

// ---------------------------------------------------------------------------
// Prep lam: Lam = exp(-exp(nu_log) + i*exp(theta_log)), [2*NH]: re then im.
// ---------------------------------------------------------------------------
__global__ __launch_bounds__(256) void prep_lam_kernel(
    const float* __restrict__ nu_log, const float* __restrict__ theta_log,
    float* __restrict__ lam)
{
    int h = threadIdx.x;
    float mod = expf(-expf(nu_log[h]));   // |Lam| in [e^-e, e^-1]
    float ang = expf(theta_log[h]);
    lam[h]      = mod * cosf(ang);
    lam[NH + h] = mod * sinf(ang);
}

// ---------------------------------------------------------------------------
// Prep weights (bf16, transposed, complex-interleaved). gamma inlined.
// WaT: (512 x 256) [n][k].  n=2h: B_re[h][k]*gam[h]; n=2h+1: B_im[h][k]*gam[h]
// WcT: (256 x 512) [d][k].  k=2h: C_re[d][h];        k=2h+1: -C_im[d][h]
// ---------------------------------------------------------------------------
__global__ __launch_bounds__(256) void prep_w_kernel(
    const float* __restrict__ nu_log,
    const float* __restrict__ B_re, const float* __restrict__ B_im,
    const float* __restrict__ C_re, const float* __restrict__ C_im,
    bf16* __restrict__ WaT, bf16* __restrict__ WcT)
{
    int idx = blockIdx.x * 256 + threadIdx.x;   // covers 2 * 131072
    if (idx < 512 * 256) {
        int n = idx >> 8, k = idx & 255;
        int h = n >> 1;
        float mod = expf(-expf(nu_log[h]));
        float gam = sqrtf(fmaxf(1.0f - mod * mod, 1e-8f));
        float v = ((n & 1) == 0 ? B_re[h * DM + k] : B_im[h * DM + k]) * gam;
        WaT[idx] = __float2bfloat16(v);
    } else {
        int j = idx - 512 * 256;
        int d = j >> 9, k = j & 511;
        int h = k >> 1;
        float v = ((k & 1) == 0) ? C_re[d * NH + h] : -C_im[d * NH + h];
        WcT[j] = __float2bfloat16(v);
    }
}

// ---------------------------------------------------------------------------
// Convert x (f32) -> xb (bf16), x8 vectorized. xb parks in d_out's first half.
// ---------------------------------------------------------------------------
__global__ __launch_bounds__(256) void cvt_kernel(
    const float* __restrict__ x, bf16* __restrict__ xb)
{
    size_t i = ((size_t)blockIdx.x * 256 + threadIdx.x) * 8;
    float4 a = *(const float4*)(x + i);
    float4 b = *(const float4*)(x + i + 4);
    union { bf16 h[8]; int4 v; } u;
    u.h[0] = __float2bfloat16(a.x); u.h[1] = __float2bfloat16(a.y);
    u.h[2] = __float2bfloat16(a.z); u.h[3] = __float2bfloat16(a.w);
    u.h[4] = __float2bfloat16(b.x); u.h[5] = __float2bfloat16(b.y);
    u.h[6] = __float2bfloat16(b.z); u.h[7] = __float2bfloat16(b.w);
    *(int4*)(xb + i) = u.v;
}

// ---------------------------------------------------------------------------
// Stage A GEMM: Bu[m][n] = sum_k xb[m][k]*WaT[n][k]
// 128x128 tile, BK=64 (4 k-iters), 4 waves 2x2, 16B-slot XOR swizzle via
// pre-swizzled global source (m173/m201). Unchanged from round 2.
// ---------------------------------------------------------------------------
__global__ __launch_bounds__(256) void gemm_a_kernel(
    const bf16* __restrict__ A,    // xb (M,256)
    const bf16* __restrict__ BT,   // WaT (512,256)
    bf16* __restrict__ Cb)         // Bu (M,512)
{
    __shared__ bf16 sA[128 * 64];   // 16 KB, swizzled
    __shared__ bf16 sB[128 * 64];   // 16 KB, swizzled

    const int tid  = threadIdx.x;
    const int lane = tid & 63;
    const int wid  = tid >> 6;

    const int bid = blockIdx.x;          // 2048 blocks
    const int xcd = bid & 7;
    const int sl  = bid >> 3;
    const int nt  = sl & 3;              // 4 n-tiles
    const int mt  = xcd * 64 + (sl >> 2);
    const int m0  = mt * 128;
    const int n0  = nt * 128;

    const int tm  = (wid >> 1) * 64;
    const int tn  = (wid & 1) * 64;
    const int l15 = lane & 15;
    const int q   = lane >> 4;

    // staging geometry: one async16 round = 8 rows x 64 cols (1 KB).
    const int r8 = lane >> 3;            // row within 8-row group = row&7
    const int s8 = lane & 7;             // physical 16B slot
    const int scol = (s8 ^ r8) * 8;      // pre-swizzled global col (elems)

    const bf16* gA = A  + (size_t)(m0 + wid * 32 + r8) * 256 + scol;
    const bf16* gB = BT + (size_t)(n0 + wid * 32 + r8) * 256 + scol;
    const size_t g8 = (size_t)8 * 256;   // 8 global rows
    bf16* lA = sA + wid * 32 * 64;
    bf16* lB = sB + wid * 32 * 64;

    f32x4 acc[4][4];
    #pragma unroll
    for (int i = 0; i < 4; ++i)
        #pragma unroll
        for (int j = 0; j < 4; ++j) acc[i][j] = (f32x4){0.f, 0.f, 0.f, 0.f};

    for (int k0 = 0; k0 < 256; k0 += 64) {
        #pragma unroll
        for (int rr = 0; rr < 4; ++rr) {
            async16(gA + rr * g8, lA + rr * 8 * 64);
            async16(gB + rr * g8, lB + rr * 8 * 64);
        }
        gA += 64; gB += 64;
        __syncthreads();

        #pragma unroll
        for (int kk = 0; kk < 2; ++kk) {
            bf16x8 af[4], bfr[4];
            #pragma unroll
            for (int i = 0; i < 4; ++i) {
                int ra = tm + i * 16 + l15;
                int sa = ((kk * 4 + q) ^ (ra & 7)) * 16;
                af[i]  = *(const bf16x8*)((const char*)sA + (size_t)ra * 128 + sa);
                int rb = tn + i * 16 + l15;
                int sb = ((kk * 4 + q) ^ (rb & 7)) * 16;
                bfr[i] = *(const bf16x8*)((const char*)sB + (size_t)rb * 128 + sb);
            }
            #pragma unroll
            for (int i = 0; i < 4; ++i)
                #pragma unroll
                for (int j = 0; j < 4; ++j)
                    acc[i][j] = __builtin_amdgcn_mfma_f32_16x16x32_bf16(
                        af[i], bfr[j], acc[i][j], 0, 0, 0);
        }
        __syncthreads();
    }

    // C/D layout: col=lane&15, row=q*4+reg (m89/m91-verified)
    #pragma unroll
    for (int j = 0; j < 4; ++j) {
        int col = n0 + tn + j * 16 + l15;
        #pragma unroll
        for (int i = 0; i < 4; ++i) {
            #pragma unroll
            for (int r = 0; r < 4; ++r) {
                int row = m0 + tm + i * 16 + q * 4 + r;
                Cb[(size_t)row * 512 + col] = __float2bfloat16(acc[i][j][r]);
            }
        }
    }
}

// ---------------------------------------------------------------------------
// Fused scan + stage C. Block = (2 batches, 32-t chunk): 1024 blocks x 512
// threads (8 waves). M = 64 rows (a = tl*2 + bi).
// Phase 1: 512 scan chains; halo 8 (|Lam|^8 <= 3.4e-4, an order below bf16
//   rounding of h itself); start flags as per-b ballot masks (SGPR).
//   h -> sH with 16B-slot XOR swizzle (slot ^= row&7), 1024 B row stride.
// Phase 2: out[64x256] = sH @ WcT^T + D*x, K=512. B comes from global WcT
//   (L2-resident, 256 KB) via REGISTER double-buffered prefetch: loads for
//   k+1 issue before the MFMA cluster for k (T14 issue-early). ZERO barriers
//   in the k-loop; the only barrier is the sH publish. vs round-1's failed
//   direct-load variant: +explicit prefetch, +16 waves/CU (2 blocks of 512
//   at 65.6 KB LDS) to hide residual L2 latency.
// ---------------------------------------------------------------------------
#define SC  32
#define HL  8
#define PF  8     // scan prefetch depth

__global__ __launch_bounds__(512, 4) void scan_gemmc_kernel(
    const bf16* __restrict__ Bu,     // (M,512)
    const bf16* __restrict__ WcT,    // (256,512)
    const float* __restrict__ lam,   // [2*NH]
    const int* __restrict__ starts,  // (T,B)
    const float* __restrict__ state_re, const float* __restrict__ state_im,
    const float* __restrict__ x,     // (M,256) f32
    const float* __restrict__ Dvec,  // (256,)
    float* __restrict__ out)         // (M,256) f32
{
    __shared__ bf16 sH[64 * 512];    // 65536 B, XOR-swizzled
    __shared__ unsigned long long sMask[2];

    const int tid = threadIdx.x;
    const int bg  = blockIdx.x & 7;          // batch pair
    const int c   = blockIdx.x >> 3;         // t-chunk
    const int b0  = bg * 2;
    const int t0  = c * SC;
    const int tstart = (c == 0) ? 0 : t0 - HL;
    const int nIter  = t0 + SC - tstart;     // 32 or 40 (both % PF == 0)

    const int bi = tid >> 8;                 // 0/1: which batch of the pair
    const int h  = tid & 255;                // complex head
    const int b  = b0 + bi;

    // start-bit masks: wave 0 -> b0, wave 4 -> b0+1 (ballot over t)
    const int wv = tid >> 6;
    if (wv == 0 || wv == 4) {
        int lane = tid & 63;
        int st = (lane < nIter) ? starts[(tstart + lane) * BATCH + b0 + (wv >> 2)] : 0;
        unsigned long long mk = __ballot(st != 0);
        if (lane == 0) sMask[wv >> 2] = mk;
    }
    __syncthreads();
    const unsigned long long mask = sMask[bi];   // wave-uniform -> SGPR

    // ---- Phase 1: scan (thread = complex head of one batch) ----
    float lr = lam[h], li = lam[NH + h];
    float hre = 0.0f, him = 0.0f;
    if (c == 0) { hre = state_re[b * NH + h]; him = state_im[b * NH + h]; }

    const bf16* bp = Bu + ((size_t)tstart * BATCH + b) * 512 + 2 * h;
    const size_t tstride = (size_t)BATCH * 512;   // elems per t step

    unsigned int vbuf[PF];
    #pragma unroll
    for (int p = 0; p < PF; ++p)
        vbuf[p] = (p < nIter) ? *(const unsigned int*)(bp + p * tstride) : 0u;

    char* sHB = (char*)sH;
    const int skip = nIter - SC;   // halo iterations before t0
    for (int base = 0; base < nIter; base += PF) {
        #pragma unroll
        for (int p = 0; p < PF; ++p) {
            int it = base + p;
            unsigned int v = vbuf[p];
            int tp = it + PF;
            if (tp < nIter)
                vbuf[p] = *(const unsigned int*)(bp + (size_t)tp * tstride);
            float bre = __uint_as_float(v << 16);
            float bim = __uint_as_float(v & 0xffff0000u);
            int st = (int)((mask >> it) & 1ull);
            float nr = st ? bre : fmaf(lr, hre, fmaf(-li, him, bre));
            float ni = st ? bim : fmaf(lr, him, fmaf(li, hre, bim));
            hre = nr; him = ni;
            int tl = it - skip;
            if (tl >= 0) {
                int a = tl * 2 + bi;                  // GEMM A-row
                int slot = (h >> 2) ^ (a & 7);        // 16B-slot XOR swizzle
                unsigned int packed =
                    ((unsigned int)f2bf_bits(him) << 16) | f2bf_bits(hre);
                *(unsigned int*)(sHB + a * 1024 + slot * 16 + (h & 3) * 4) = packed;
            }
        }
    }
    __syncthreads();   // sH published -- the ONLY barrier in this kernel

    // ---- Phase 2: GEMM 64x256, K=512; A from swizzled sH (LDS);
    //      B register-double-buffered direct from WcT (L2). No barriers. ----
    const int lane = tid & 63;
    const int w    = tid >> 6;          // 0..7
    const int wm   = w >> 2;            // rows wm*32..+32
    const int wn   = w & 3;             // cols wn*64..+64
    const int l15  = lane & 15;
    const int q    = lane >> 4;

    f32x4 acc[2][4];
    #pragma unroll
    for (int i = 0; i < 2; ++i)
        #pragma unroll
        for (int j = 0; j < 4; ++j) acc[i][j] = (f32x4){0.f, 0.f, 0.f, 0.f};

    // lane's B window: WcT[wn*64 + j*16 + l15][k0 + q*8 .. +8]  (16 B)
    const bf16* wrow = WcT + (size_t)(wn * 64 + l15) * 512 + q * 8;

    bf16x8 bA[4], bB[4];
    #pragma unroll
    for (int j = 0; j < 4; ++j)
        bA[j] = *(const bf16x8*)(wrow + (size_t)j * 16 * 512);

    #pragma unroll
    for (int k = 0; k < 16; k += 2) {
        // issue k+1 loads before MFMA(k): latency hides under MFMA+ds_read
        #pragma unroll
        for (int j = 0; j < 4; ++j)
            bB[j] = *(const bf16x8*)(wrow + (size_t)j * 16 * 512 + (k + 1) * 32);
        {
            const int k0 = k * 32;
            bf16x8 af[2];
            #pragma unroll
            for (int i = 0; i < 2; ++i) {
                int a = wm * 32 + i * 16 + l15;
                int slot = ((k0 >> 3) + q) ^ (a & 7);
                af[i] = *(const bf16x8*)(sHB + a * 1024 + slot * 16);
            }
            #pragma unroll
            for (int i = 0; i < 2; ++i)
                #pragma unroll
                for (int j = 0; j < 4; ++j)
                    acc[i][j] = __builtin_amdgcn_mfma_f32_16x16x32_bf16(
                        af[i], bA[j], acc[i][j], 0, 0, 0);
        }
        if (k + 2 < 16) {
            #pragma unroll
            for (int j = 0; j < 4; ++j)
                bA[j] = *(const bf16x8*)(wrow + (size_t)j * 16 * 512 + (k + 2) * 32);
        }
        {
            const int k0 = (k + 1) * 32;
            bf16x8 af[2];
            #pragma unroll
            for (int i = 0; i < 2; ++i) {
                int a = wm * 32 + i * 16 + l15;
                int slot = ((k0 >> 3) + q) ^ (a & 7);
                af[i] = *(const bf16x8*)(sHB + a * 1024 + slot * 16);
            }
            #pragma unroll
            for (int i = 0; i < 2; ++i)
                #pragma unroll
                for (int j = 0; j < 4; ++j)
                    acc[i][j] = __builtin_amdgcn_mfma_f32_16x16x32_bf16(
                        af[i], bB[j], acc[i][j], 0, 0, 0);
        }
    }

    // Epilogue: a = tl*2 + bi -> m = (t0+tl)*16 + b0 + bi, + D*x skip
    #pragma unroll
    for (int j = 0; j < 4; ++j) {
        int col = wn * 64 + j * 16 + l15;
        float dv = Dvec[col];
        #pragma unroll
        for (int i = 0; i < 2; ++i) {
            #pragma unroll
            for (int r = 0; r < 4; ++r) {
                int a = wm * 32 + i * 16 + q * 4 + r;
                size_t m = (size_t)(t0 + (a >> 1)) * BATCH + b0 + (a & 1);
                out[m * 256 + col] = acc[i][j][r] + dv * x[m * 256 + col];
            }
        }
    }
}

// ---------------------------------------------------------------------------
// Launch. Workspace: lam 2KB | WaT 256KB | WcT 256KB | Bu 64MB (~65MB total).
// xb (32MB) parks in d_out's first half: consumed only by stage A, which is
// stream-ordered before the fused kernel overwrites d_out.
// ---------------------------------------------------------------------------
extern "C" void kernel_launch(void* const* d_in, const int* in_sizes, int n_in,
                              void* d_out, int out_size, void* d_ws, size_t ws_size,
                              hipStream_t stream)
{
    const float* x         = (const float*)d_in[0];
    const int*   starts    = (const int*)d_in[1];
    const float* state_re  = (const float*)d_in[2];
    const float* state_im  = (const float*)d_in[3];
    const float* nu_log    = (const float*)d_in[4];
    const float* theta_log = (const float*)d_in[5];
    const float* B_re      = (const float*)d_in[6];
    const float* B_im      = (const float*)d_in[7];
    const float* C_re      = (const float*)d_in[8];
    const float* C_im      = (const float*)d_in[9];
    const float* Dvec      = (const float*)d_in[10];
    float* out = (float*)d_out;

    char* ws = (char*)d_ws;
    float* lam = (float*)ws;                            // 2*NH f32
    bf16*  WaT = (bf16*)(ws + 4096);                    // 512x256 bf16
    bf16*  WcT = (bf16*)(ws + 4096 + 512 * 256 * 2);    // 256x512 bf16
    bf16*  Bu  = (bf16*)(ws + (1 << 20));               // 65536x512 bf16 (64MB)
    bf16*  xb  = (bf16*)d_out;                          // 32MB, dead by fused

    prep_lam_kernel<<<1, 256, 0, stream>>>(nu_log, theta_log, lam);
    prep_w_kernel<<<1024, 256, 0, stream>>>(nu_log, B_re, B_im, C_re, C_im, WaT, WcT);
    cvt_kernel<<<M_TOT * DM / (256 * 8), 256, 0, stream>>>(x, xb);

    // Stage A: Bu = xb @ WaT^T   (M=65536, K=256, N=512). 2048 blocks.
    gemm_a_kernel<<<2048, 256, 0, stream>>>(xb, WaT, Bu);

    // Fused scan + stage C: 1024 blocks = (chunk, batch-pair), 512 threads.
    scan_gemmc_kernel<<<(T_LEN / SC) * (BATCH / 2), 512, 0, stream>>>(
        Bu, WcT, lam, starts, state_re, state_im, x, Dvec, out);
}

// Round 4
// 224.453 us; speedup vs baseline: 1.1499x; 1.1499x over previous
//
#include <hip/hip_runtime.h>
#include <hip/hip_bf16.h>

// Problem constants (T, B, H, D_MODEL) = (4096, 16, 256, 256)
#define T_LEN 4096
#define BATCH 16
#define NH    256
#define DM    256
#define M_TOT (T_LEN * BATCH)   // 65536 rows for both GEMMs

typedef __hip_bfloat16 bf16;
typedef __attribute__((ext_vector_type(8))) short bf16x8;  // 8 bf16 = 4 VGPRs
typedef __attribute__((ext_vector_type(4))) float f32x4;

// manual RTNE f32->bf16 (bit-level)
__device__ __forceinline__ unsigned short f2bf_bits(float f) {
    unsigned int u = __float_as_uint(f);
    return (unsigned short)((u + 0x7fffu + ((u >> 16) & 1u)) >> 16);
}

// async global->LDS, 16 B per lane. LDS dest must be wave-uniform base;
// HW scatters lane i to base + i*16 (m97/m104 contract -> LDS stays linear;
// swizzled layouts are achieved by pre-swizzling the GLOBAL source, m173).
typedef const unsigned int __attribute__((address_space(1)))* gas_ptr;
typedef unsigned int __attribute__((address_space(3)))* las_ptr;
__device__ __forceinline__ void async16(const bf16* g, bf16* l) {
    __builtin_amdgcn_global_load_lds((gas_ptr)g, (las_ptr)l, 16, 0, 0);
}

// ---------------------------------------------------------------------------
// Prep lam: Lam = exp(-exp(nu_log) + i*exp(theta_log)), [2*NH]: re then im.
// ---------------------------------------------------------------------------
__global__ __launch_bounds__(256) void prep_lam_kernel(
    const float* __restrict__ nu_log, const float* __restrict__ theta_log,
    float* __restrict__ lam)
{
    int h = threadIdx.x;
    float mod = expf(-expf(nu_log[h]));   // |Lam| in [e^-e, e^-1]
    float ang = expf(theta_log[h]);
    lam[h]      = mod * cosf(ang);
    lam[NH + h] = mod * sinf(ang);
}

// ---------------------------------------------------------------------------
// Prep weights (bf16, transposed, complex-interleaved). gamma inlined.
// WaT: (512 x 256) [n][k].  n=2h: B_re[h][k]*gam[h]; n=2h+1: B_im[h][k]*gam[h]
// WcT: (256 x 512) [d][k].  k=2h: C_re[d][h];        k=2h+1: -C_im[d][h]
// ---------------------------------------------------------------------------
__global__ __launch_bounds__(256) void prep_w_kernel(
    const float* __restrict__ nu_log,
    const float* __restrict__ B_re, const float* __restrict__ B_im,
    const float* __restrict__ C_re, const float* __restrict__ C_im,
    bf16* __restrict__ WaT, bf16* __restrict__ WcT)
{
    int idx = blockIdx.x * 256 + threadIdx.x;   // covers 2 * 131072
    if (idx < 512 * 256) {
        int n = idx >> 8, k = idx & 255;
        int h = n >> 1;
        float mod = expf(-expf(nu_log[h]));
        float gam = sqrtf(fmaxf(1.0f - mod * mod, 1e-8f));
        float v = ((n & 1) == 0 ? B_re[h * DM + k] : B_im[h * DM + k]) * gam;
        WaT[idx] = __float2bfloat16(v);
    } else {
        int j = idx - 512 * 256;
        int d = j >> 9, k = j & 511;
        int h = k >> 1;
        float v = ((k & 1) == 0) ? C_re[d * NH + h] : -C_im[d * NH + h];
        WcT[j] = __float2bfloat16(v);
    }
}

// ---------------------------------------------------------------------------
// Convert x (f32) -> xb (bf16), x8 vectorized. xb parks in d_out's first half.
// ---------------------------------------------------------------------------
__global__ __launch_bounds__(256) void cvt_kernel(
    const float* __restrict__ x, bf16* __restrict__ xb)
{
    size_t i = ((size_t)blockIdx.x * 256 + threadIdx.x) * 8;
    float4 a = *(const float4*)(x + i);
    float4 b = *(const float4*)(x + i + 4);
    union { bf16 h[8]; int4 v; } u;
    u.h[0] = __float2bfloat16(a.x); u.h[1] = __float2bfloat16(a.y);
    u.h[2] = __float2bfloat16(a.z); u.h[3] = __float2bfloat16(a.w);
    u.h[4] = __float2bfloat16(b.x); u.h[5] = __float2bfloat16(b.y);
    u.h[6] = __float2bfloat16(b.z); u.h[7] = __float2bfloat16(b.w);
    *(int4*)(xb + i) = u.v;
}

// ---------------------------------------------------------------------------
// Stage A GEMM: Bu[m][n] = sum_k xb[m][k]*WaT[n][k]
// 128x128 tile, BK=64 (4 k-iters), 4 waves 2x2, 16B-slot XOR swizzle via
// pre-swizzled global source (m173/m201). Unchanged from round 2 (verified).
// ---------------------------------------------------------------------------
__global__ __launch_bounds__(256) void gemm_a_kernel(
    const bf16* __restrict__ A,    // xb (M,256)
    const bf16* __restrict__ BT,   // WaT (512,256)
    bf16* __restrict__ Cb)         // Bu (M,512)
{
    __shared__ bf16 sA[128 * 64];   // 16 KB, swizzled
    __shared__ bf16 sB[128 * 64];   // 16 KB, swizzled

    const int tid  = threadIdx.x;
    const int lane = tid & 63;
    const int wid  = tid >> 6;

    const int bid = blockIdx.x;          // 2048 blocks
    const int xcd = bid & 7;
    const int sl  = bid >> 3;
    const int nt  = sl & 3;              // 4 n-tiles
    const int mt  = xcd * 64 + (sl >> 2);
    const int m0  = mt * 128;
    const int n0  = nt * 128;

    const int tm  = (wid >> 1) * 64;
    const int tn  = (wid & 1) * 64;
    const int l15 = lane & 15;
    const int q   = lane >> 4;

    // staging geometry: one async16 round = 8 rows x 64 cols (1 KB).
    const int r8 = lane >> 3;            // row within 8-row group = row&7
    const int s8 = lane & 7;             // physical 16B slot
    const int scol = (s8 ^ r8) * 8;      // pre-swizzled global col (elems)

    const bf16* gA = A  + (size_t)(m0 + wid * 32 + r8) * 256 + scol;
    const bf16* gB = BT + (size_t)(n0 + wid * 32 + r8) * 256 + scol;
    const size_t g8 = (size_t)8 * 256;   // 8 global rows
    bf16* lA = sA + wid * 32 * 64;
    bf16* lB = sB + wid * 32 * 64;

    f32x4 acc[4][4];
    #pragma unroll
    for (int i = 0; i < 4; ++i)
        #pragma unroll
        for (int j = 0; j < 4; ++j) acc[i][j] = (f32x4){0.f, 0.f, 0.f, 0.f};

    for (int k0 = 0; k0 < 256; k0 += 64) {
        #pragma unroll
        for (int rr = 0; rr < 4; ++rr) {
            async16(gA + rr * g8, lA + rr * 8 * 64);
            async16(gB + rr * g8, lB + rr * 8 * 64);
        }
        gA += 64; gB += 64;
        __syncthreads();

        #pragma unroll
        for (int kk = 0; kk < 2; ++kk) {
            bf16x8 af[4], bfr[4];
            #pragma unroll
            for (int i = 0; i < 4; ++i) {
                int ra = tm + i * 16 + l15;
                int sa = ((kk * 4 + q) ^ (ra & 7)) * 16;
                af[i]  = *(const bf16x8*)((const char*)sA + (size_t)ra * 128 + sa);
                int rb = tn + i * 16 + l15;
                int sb = ((kk * 4 + q) ^ (rb & 7)) * 16;
                bfr[i] = *(const bf16x8*)((const char*)sB + (size_t)rb * 128 + sb);
            }
            #pragma unroll
            for (int i = 0; i < 4; ++i)
                #pragma unroll
                for (int j = 0; j < 4; ++j)
                    acc[i][j] = __builtin_amdgcn_mfma_f32_16x16x32_bf16(
                        af[i], bfr[j], acc[i][j], 0, 0, 0);
        }
        __syncthreads();
    }

    // C/D layout: col=lane&15, row=q*4+reg (m89/m91-verified)
    #pragma unroll
    for (int j = 0; j < 4; ++j) {
        int col = n0 + tn + j * 16 + l15;
        #pragma unroll
        for (int i = 0; i < 4; ++i) {
            #pragma unroll
            for (int r = 0; r < 4; ++r) {
                int row = m0 + tm + i * 16 + q * 4 + r;
                Cb[(size_t)row * 512 + col] = __float2bfloat16(acc[i][j][r]);
            }
        }
    }
}

// ---------------------------------------------------------------------------
// Fused scan + stage C (round-2 structure + surgical fixes).
// Block = (2 batches, 32-t chunk): 1024 blocks x 512 threads (8 waves), M=64.
// Phase 1: 512 scan chains; halo 8 (|Lam|^8 <= 3.4e-4 << bf16 rounding);
//   start flags via per-wave __ballot (no LDS, no extra barrier).
//   h -> sH with 16B-slot XOR swizzle (slot ^= row&7), 1024 B row stride.
//   sB chunk for k0=0 is prefetched BEFORE the scan (overlaps fully).
// Phase 2: out[64x256] = sH @ WcT^T + D*x, K=512, BK=32 async16-staged sB.
//   sB slot-swizzle: phys_slot = q ^ ((row>>1)&3) applied on the global
//   source (write) and the ds_read (read) -> 8-way conflict becomes 2-way.
//   Loop order: read frags -> barrier -> issue stage(k+1) -> MFMA -> barrier,
//   so each stage round has MFMA-time head start before its drain.
// LDS: sH 64 KB + sB 16 KB = 81920 B exactly -> 2 blocks/CU (16 waves/CU).
// ---------------------------------------------------------------------------
#define SC  32
#define HL  8
#define PF  8     // scan prefetch depth

__global__ __launch_bounds__(512) void scan_gemmc_kernel(
    const bf16* __restrict__ Bu,     // (M,512)
    const bf16* __restrict__ WcT,    // (256,512)
    const float* __restrict__ lam,   // [2*NH]
    const int* __restrict__ starts,  // (T,B)
    const float* __restrict__ state_re, const float* __restrict__ state_im,
    const float* __restrict__ x,     // (M,256) f32
    const float* __restrict__ Dvec,  // (256,)
    float* __restrict__ out)         // (M,256) f32
{
    __shared__ bf16 sH[64 * 512];    // 65536 B, XOR-swizzled
    __shared__ bf16 sB[256 * 32];    // 16384 B, slot-swizzled

    const int tid = threadIdx.x;
    const int bg  = blockIdx.x & 7;          // batch pair
    const int c   = blockIdx.x >> 3;         // t-chunk
    const int b0  = bg * 2;
    const int t0  = c * SC;
    const int tstart = (c == 0) ? 0 : t0 - HL;
    const int nIter  = t0 + SC - tstart;     // 32 or 40 (both % PF == 0)

    const int bi = tid >> 8;                 // 0/1: which batch of the pair
    const int h  = tid & 255;                // complex head
    const int b  = b0 + bi;

    // Phase-2 staging pointers (wave-level), set up early so we can prefetch.
    const int lane = tid & 63;
    const int w    = tid >> 6;               // 0..7
    {
        // nothing
    }
    const int rsub = lane >> 2;              // 0..15: row within 16-row group
    const int sp   = lane & 3;               // physical 16B slot
    const int qlog = sp ^ ((rsub >> 1) & 3); // logical q stored at this slot
    const bf16* gBs = WcT + (size_t)(w * 32 + rsub) * 512 + qlog * 8;
    bf16* lBs = sB + w * 32 * 32;            // wave-uniform LDS base

    // start-bit mask: every wave ballots its own batch (wave 0-3 -> b0,
    // wave 4-7 -> b0+1). No LDS, no barrier.
    unsigned long long mask;
    {
        int st = (lane < nIter) ? starts[(tstart + lane) * BATCH + b] : 0;
        mask = __ballot(st != 0);
    }

    // Prefetch sB chunk for k0=0: overlaps the entire phase-1 scan.
    async16(gBs,            lBs);
    async16(gBs + 16 * 512, lBs + 16 * 32);

    // ---- Phase 1: scan (thread = complex head of one batch) ----
    float lr = lam[h], li = lam[NH + h];
    float hre = 0.0f, him = 0.0f;
    if (c == 0) { hre = state_re[b * NH + h]; him = state_im[b * NH + h]; }

    const bf16* bp = Bu + ((size_t)tstart * BATCH + b) * 512 + 2 * h;
    const size_t tstride = (size_t)BATCH * 512;   // elems per t step

    unsigned int vbuf[PF];
    #pragma unroll
    for (int p = 0; p < PF; ++p)
        vbuf[p] = *(const unsigned int*)(bp + p * tstride);   // PF <= 32 <= nIter

    char* sHB = (char*)sH;
    const int skip = nIter - SC;   // halo iterations before t0
    for (int base = 0; base < nIter; base += PF) {
        #pragma unroll
        for (int p = 0; p < PF; ++p) {
            int it = base + p;
            unsigned int v = vbuf[p];
            int tp = it + PF;
            if (tp < nIter)
                vbuf[p] = *(const unsigned int*)(bp + (size_t)tp * tstride);
            float bre = __uint_as_float(v << 16);
            float bim = __uint_as_float(v & 0xffff0000u);
            int st = (int)((mask >> it) & 1ull);
            float nr = st ? bre : fmaf(lr, hre, fmaf(-li, him, bre));
            float ni = st ? bim : fmaf(lr, him, fmaf(li, hre, bim));
            hre = nr; him = ni;
            int tl = it - skip;
            if (tl >= 0) {
                int a = tl * 2 + bi;                  // GEMM A-row
                int slot = (h >> 2) ^ (a & 7);        // 16B-slot XOR swizzle
                unsigned int packed =
                    ((unsigned int)f2bf_bits(him) << 16) | f2bf_bits(hre);
                *(unsigned int*)(sHB + a * 1024 + slot * 16 + (h & 3) * 4) = packed;
            }
        }
    }
    __syncthreads();   // sH published; sB(k0=0) drained (implicit vmcnt 0)

    // ---- Phase 2: GEMM 64x256, K=512; A from swizzled sH, B staged in sB ----
    const int wm   = w >> 2;            // rows wm*32..+32
    const int wn   = w & 3;             // cols wn*64..+64
    const int l15  = lane & 15;
    const int q    = lane >> 4;
    const int slotq = q ^ ((l15 >> 1) & 3);   // sB read slot (row-invariant)

    f32x4 acc[2][4];
    #pragma unroll
    for (int i = 0; i < 2; ++i)
        #pragma unroll
        for (int j = 0; j < 4; ++j) acc[i][j] = (f32x4){0.f, 0.f, 0.f, 0.f};

    for (int it = 0; it < 16; ++it) {
        const int k0 = it * 32;

        bf16x8 af[2], bfr[4];
        #pragma unroll
        for (int i = 0; i < 2; ++i) {
            int a = wm * 32 + i * 16 + l15;
            int slot = ((k0 >> 3) + q) ^ (a & 7);
            af[i] = *(const bf16x8*)(sHB + a * 1024 + slot * 16);
        }
        #pragma unroll
        for (int j = 0; j < 4; ++j)
            bfr[j] = *(const bf16x8*)&sB[(wn * 64 + j * 16 + l15) * 32 + slotq * 8];

        __syncthreads();   // all waves have read sB (own lgkm drained pre-bar)

        if (it < 15) {     // begin overwriting sB for k0+32; MFMA hides part
            async16(gBs + k0 + 32,            lBs);
            async16(gBs + 16 * 512 + k0 + 32, lBs + 16 * 32);
        }

        #pragma unroll
        for (int i = 0; i < 2; ++i)
            #pragma unroll
            for (int j = 0; j < 4; ++j)
                acc[i][j] = __builtin_amdgcn_mfma_f32_16x16x32_bf16(
                    af[i], bfr[j], acc[i][j], 0, 0, 0);

        if (it < 15) __syncthreads();   // stage(it+1) landed (implicit vmcnt 0)
    }

    // Epilogue: a = tl*2 + bi -> m = (t0+tl)*16 + b0 + bi, + D*x skip
    #pragma unroll
    for (int j = 0; j < 4; ++j) {
        int col = wn * 64 + j * 16 + l15;
        float dv = Dvec[col];
        #pragma unroll
        for (int i = 0; i < 2; ++i) {
            #pragma unroll
            for (int r = 0; r < 4; ++r) {
                int a = wm * 32 + i * 16 + q * 4 + r;
                size_t m = (size_t)(t0 + (a >> 1)) * BATCH + b0 + (a & 1);
                out[m * 256 + col] = acc[i][j][r] + dv * x[m * 256 + col];
            }
        }
    }
}

// ---------------------------------------------------------------------------
// Launch. Workspace: lam 2KB | WaT 256KB | WcT 256KB | Bu 64MB (~65MB total).
// xb (32MB) parks in d_out's first half: consumed only by stage A, which is
// stream-ordered before the fused kernel overwrites d_out.
// ---------------------------------------------------------------------------
extern "C" void kernel_launch(void* const* d_in, const int* in_sizes, int n_in,
                              void* d_out, int out_size, void* d_ws, size_t ws_size,
                              hipStream_t stream)
{
    const float* x         = (const float*)d_in[0];
    const int*   starts    = (const int*)d_in[1];
    const float* state_re  = (const float*)d_in[2];
    const float* state_im  = (const float*)d_in[3];
    const float* nu_log    = (const float*)d_in[4];
    const float* theta_log = (const float*)d_in[5];
    const float* B_re      = (const float*)d_in[6];
    const float* B_im      = (const float*)d_in[7];
    const float* C_re      = (const float*)d_in[8];
    const float* C_im      = (const float*)d_in[9];
    const float* Dvec      = (const float*)d_in[10];
    float* out = (float*)d_out;

    char* ws = (char*)d_ws;
    float* lam = (float*)ws;                            // 2*NH f32
    bf16*  WaT = (bf16*)(ws + 4096);                    // 512x256 bf16
    bf16*  WcT = (bf16*)(ws + 4096 + 512 * 256 * 2);    // 256x512 bf16
    bf16*  Bu  = (bf16*)(ws + (1 << 20));               // 65536x512 bf16 (64MB)
    bf16*  xb  = (bf16*)d_out;                          // 32MB, dead by fused

    prep_lam_kernel<<<1, 256, 0, stream>>>(nu_log, theta_log, lam);
    prep_w_kernel<<<1024, 256, 0, stream>>>(nu_log, B_re, B_im, C_re, C_im, WaT, WcT);
    cvt_kernel<<<M_TOT * DM / (256 * 8), 256, 0, stream>>>(x, xb);

    // Stage A: Bu = xb @ WaT^T   (M=65536, K=256, N=512). 2048 blocks.
    gemm_a_kernel<<<2048, 256, 0, stream>>>(xb, WaT, Bu);

    // Fused scan + stage C: 1024 blocks = (chunk, batch-pair), 512 threads.
    scan_gemmc_kernel<<<(T_LEN / SC) * (BATCH / 2), 512, 0, stream>>>(
        Bu, WcT, lam, starts, state_re, state_im, x, Dvec, out);
}

// Round 5
// 217.851 us; speedup vs baseline: 1.1847x; 1.0303x over previous
//
#include <hip/hip_runtime.h>
#include <hip/hip_bf16.h>

// Problem constants (T, B, H, D_MODEL) = (4096, 16, 256, 256)
#define T_LEN 4096
#define BATCH 16
#define NH    256
#define DM    256
#define M_TOT (T_LEN * BATCH)   // 65536 rows for both GEMMs

typedef __hip_bfloat16 bf16;
typedef __attribute__((ext_vector_type(8))) short bf16x8;  // 8 bf16 = 4 VGPRs
typedef __attribute__((ext_vector_type(4))) float f32x4;

// manual RTNE f32->bf16 (bit-level) -- same rounding as __float2bfloat16
__device__ __forceinline__ unsigned short f2bf_bits(float f) {
    unsigned int u = __float_as_uint(f);
    return (unsigned short)((u + 0x7fffu + ((u >> 16) & 1u)) >> 16);
}

__device__ __forceinline__ bf16x8 pack8(f32x4 lo, f32x4 hi) {
    union { unsigned short s[8]; bf16x8 v; } u;
    #pragma unroll
    for (int j = 0; j < 4; ++j) {
        u.s[j]     = f2bf_bits(lo[j]);
        u.s[4 + j] = f2bf_bits(hi[j]);
    }
    return u.v;
}

// async global->LDS, 16 B per lane. LDS dest must be wave-uniform base;
// HW scatters lane i to base + i*16 (m97/m104 contract -> LDS stays linear;
// swizzled layouts are achieved by pre-swizzling the GLOBAL source, m173).
typedef const unsigned int __attribute__((address_space(1)))* gas_ptr;
typedef unsigned int __attribute__((address_space(3)))* las_ptr;
__device__ __forceinline__ void async16(const bf16* g, bf16* l) {
    __builtin_amdgcn_global_load_lds((gas_ptr)g, (las_ptr)l, 16, 0, 0);
}
__device__ __forceinline__ void async16f(const float* g, float* l) {
    __builtin_amdgcn_global_load_lds((gas_ptr)g, (las_ptr)l, 16, 0, 0);
}

// ---------------------------------------------------------------------------
// Prep weights (bf16, transposed, complex-interleaved) + lam (block 1024).
// WaT: (512 x 256) [n][k].  n=2h: B_re[h][k]*gam[h]; n=2h+1: B_im[h][k]*gam[h]
// WcT: (256 x 512) [d][k].  k=2h: C_re[d][h];        k=2h+1: -C_im[d][h]
// lam: [2*NH] re then im.
// ---------------------------------------------------------------------------
__global__ __launch_bounds__(256) void prep_w_kernel(
    const float* __restrict__ nu_log, const float* __restrict__ theta_log,
    const float* __restrict__ B_re, const float* __restrict__ B_im,
    const float* __restrict__ C_re, const float* __restrict__ C_im,
    bf16* __restrict__ WaT, bf16* __restrict__ WcT, float* __restrict__ lam)
{
    if (blockIdx.x == 1024) {   // lam block
        int h = threadIdx.x;
        float mod = expf(-expf(nu_log[h]));   // |Lam| in [e^-e, e^-1]
        float ang = expf(theta_log[h]);
        lam[h]      = mod * cosf(ang);
        lam[NH + h] = mod * sinf(ang);
        return;
    }
    int idx = blockIdx.x * 256 + threadIdx.x;   // covers 2 * 131072
    if (idx < 512 * 256) {
        int n = idx >> 8, k = idx & 255;
        int h = n >> 1;
        float mod = expf(-expf(nu_log[h]));
        float gam = sqrtf(fmaxf(1.0f - mod * mod, 1e-8f));
        float v = ((n & 1) == 0 ? B_re[h * DM + k] : B_im[h * DM + k]) * gam;
        WaT[idx] = __float2bfloat16(v);
    } else {
        int j = idx - 512 * 256;
        int d = j >> 9, k = j & 511;
        int h = k >> 1;
        float v = ((k & 1) == 0) ? C_re[d * NH + h] : -C_im[d * NH + h];
        WcT[j] = __float2bfloat16(v);
    }
}

// ---------------------------------------------------------------------------
// Stage A GEMM (cvt fused): Bu[m][n] = sum_k bf16(x[m][k]) * WaT[n][k]
// 128x128 tile, BK=64, 4 waves 2x2. A is staged as F32 direct from x via
// global_load_lds (DMA kept; conversion happens at fragment-read: 8 scalar
// cvts per fragment vs 32 MFMA/iter). A rows are 256 B -> 16-slot XOR swizzle
// (slot ^= row&15) applied on the pre-swizzled GLOBAL source (m173); read
// side XORs the slot -> 2 lanes/bank (free). B path unchanged from r2/r4.
// LDS: sAf 32 KB (f32) + sB 16 KB = 48 KB -> 3 blocks/CU.
// ---------------------------------------------------------------------------
__global__ __launch_bounds__(256) void gemm_a_kernel(
    const float* __restrict__ X,   // x (M,256) f32
    const bf16* __restrict__ BT,   // WaT (512,256)
    bf16* __restrict__ Cb)         // Bu (M,512)
{
    __shared__ float sAf[128 * 64];  // 32 KB, f32, 16-slot swizzled 256B rows
    __shared__ bf16  sB [128 * 64];  // 16 KB, 8-slot swizzled 128B rows

    const int tid  = threadIdx.x;
    const int lane = tid & 63;
    const int wid  = tid >> 6;

    const int bid = blockIdx.x;          // 2048 blocks
    const int xcd = bid & 7;
    const int sl  = bid >> 3;
    const int nt  = sl & 3;              // 4 n-tiles
    const int mt  = xcd * 64 + (sl >> 2);
    const int m0  = mt * 128;
    const int n0  = nt * 128;

    const int tm  = (wid >> 1) * 64;
    const int tn  = (wid & 1) * 64;
    const int l15 = lane & 15;
    const int q   = lane >> 4;

    // A staging (f32): one async16 round = 4 rows x 16 slots x 16B (1 KB).
    const int r4  = lane >> 4;           // row within 4-row group
    const int s16 = lane & 15;           // physical 16B slot
    // B staging (bf16): one round = 8 rows x 8 slots x 16B (1 KB).
    const int r8 = lane >> 3;
    const int s8 = lane & 7;

    const float* gA = X  + (size_t)(m0 + wid * 32) * 256;
    const bf16*  gB = BT + (size_t)(n0 + wid * 32 + r8) * 256 + (s8 ^ r8) * 8;
    float* lA = sAf + wid * 32 * 64;     // wave-uniform LDS bases
    bf16*  lB = sB  + wid * 32 * 64;

    f32x4 acc[4][4];
    #pragma unroll
    for (int i = 0; i < 4; ++i)
        #pragma unroll
        for (int j = 0; j < 4; ++j) acc[i][j] = (f32x4){0.f, 0.f, 0.f, 0.f};

    const char* sAfB = (const char*)sAf;

    for (int k0 = 0; k0 < 256; k0 += 64) {
        // A: 8 rounds/wave (32 rows x 256 B). global col pre-swizzled.
        #pragma unroll
        for (int rr = 0; rr < 8; ++rr) {
            int row  = rr * 4 + r4;                       // 0..31 within wave
            int scol = (s16 ^ (row & 15)) * 4;            // f32 elems
            async16f(gA + (size_t)row * 256 + k0 + scol, lA + rr * 4 * 64);
        }
        // B: 4 rounds/wave (32 rows x 128 B), 8-slot swizzle (r2-verified).
        #pragma unroll
        for (int rr = 0; rr < 4; ++rr)
            async16(gB + (size_t)(rr * 8) * 256 + k0, lB + rr * 8 * 64);
        __syncthreads();

        #pragma unroll
        for (int kk = 0; kk < 2; ++kk) {
            bf16x8 af[4], bfr[4];
            #pragma unroll
            for (int i = 0; i < 4; ++i) {
                int ra = tm + i * 16 + l15;
                int g  = kk * 4 + q;                      // 32B granule 0..7
                f32x4 lo = *(const f32x4*)(sAfB + (size_t)ra * 256 +
                                           (((2 * g)     ^ (ra & 15)) * 16));
                f32x4 hi = *(const f32x4*)(sAfB + (size_t)ra * 256 +
                                           (((2 * g + 1) ^ (ra & 15)) * 16));
                af[i] = pack8(lo, hi);
                int rb = tn + i * 16 + l15;
                int sb = ((kk * 4 + q) ^ (rb & 7)) * 16;
                bfr[i] = *(const bf16x8*)((const char*)sB + (size_t)rb * 128 + sb);
            }
            #pragma unroll
            for (int i = 0; i < 4; ++i)
                #pragma unroll
                for (int j = 0; j < 4; ++j)
                    acc[i][j] = __builtin_amdgcn_mfma_f32_16x16x32_bf16(
                        af[i], bfr[j], acc[i][j], 0, 0, 0);
        }
        __syncthreads();
    }

    // C/D layout: col=lane&15, row=q*4+reg (m89/m91-verified)
    #pragma unroll
    for (int j = 0; j < 4; ++j) {
        int col = n0 + tn + j * 16 + l15;
        #pragma unroll
        for (int i = 0; i < 4; ++i) {
            #pragma unroll
            for (int r = 0; r < 4; ++r) {
                int row = m0 + tm + i * 16 + q * 4 + r;
                Cb[(size_t)row * 512 + col] = __float2bfloat16(acc[i][j][r]);
            }
        }
    }
}

// ---------------------------------------------------------------------------
// Fused scan + stage C (round-4 structure, verified 66 us -- unchanged).
// Block = (2 batches, 32-t chunk): 1024 blocks x 512 threads (8 waves), M=64.
// Phase 1: 512 scan chains; halo 8 (|Lam|^8 <= 3.4e-4 << bf16 rounding);
//   start flags via per-wave __ballot; h -> sH with 16B-slot XOR swizzle.
//   sB chunk for k0=0 prefetched BEFORE the scan (overlaps fully).
// Phase 2: out[64x256] = sH @ WcT^T + D*x, K=512, BK=32 async16-staged sB
//   with 4-slot swizzle (phys = q ^ ((row>>1)&3)).
// LDS: sH 64 KB + sB 16 KB = 81920 B exactly -> 2 blocks/CU (16 waves/CU).
// ---------------------------------------------------------------------------
#define SC  32
#define HL  8
#define PF  8     // scan prefetch depth

__global__ __launch_bounds__(512) void scan_gemmc_kernel(
    const bf16* __restrict__ Bu,     // (M,512)
    const bf16* __restrict__ WcT,    // (256,512)
    const float* __restrict__ lam,   // [2*NH]
    const int* __restrict__ starts,  // (T,B)
    const float* __restrict__ state_re, const float* __restrict__ state_im,
    const float* __restrict__ x,     // (M,256) f32
    const float* __restrict__ Dvec,  // (256,)
    float* __restrict__ out)         // (M,256) f32
{
    __shared__ bf16 sH[64 * 512];    // 65536 B, XOR-swizzled
    __shared__ bf16 sB[256 * 32];    // 16384 B, slot-swizzled

    const int tid = threadIdx.x;
    const int bg  = blockIdx.x & 7;          // batch pair
    const int c   = blockIdx.x >> 3;         // t-chunk
    const int b0  = bg * 2;
    const int t0  = c * SC;
    const int tstart = (c == 0) ? 0 : t0 - HL;
    const int nIter  = t0 + SC - tstart;     // 32 or 40 (both % PF == 0)

    const int bi = tid >> 8;                 // 0/1: which batch of the pair
    const int h  = tid & 255;                // complex head
    const int b  = b0 + bi;

    // Phase-2 staging pointers (wave-level), set up early so we can prefetch.
    const int lane = tid & 63;
    const int w    = tid >> 6;               // 0..7
    const int rsub = lane >> 2;              // 0..15: row within 16-row group
    const int sp   = lane & 3;               // physical 16B slot
    const int qlog = sp ^ ((rsub >> 1) & 3); // logical q stored at this slot
    const bf16* gBs = WcT + (size_t)(w * 32 + rsub) * 512 + qlog * 8;
    bf16* lBs = sB + w * 32 * 32;            // wave-uniform LDS base

    // start-bit mask: every wave ballots its own batch (wave 0-3 -> b0,
    // wave 4-7 -> b0+1). No LDS, no barrier.
    unsigned long long mask;
    {
        int st = (lane < nIter) ? starts[(tstart + lane) * BATCH + b] : 0;
        mask = __ballot(st != 0);
    }

    // Prefetch sB chunk for k0=0: overlaps the entire phase-1 scan.
    async16(gBs,            lBs);
    async16(gBs + 16 * 512, lBs + 16 * 32);

    // ---- Phase 1: scan (thread = complex head of one batch) ----
    float lr = lam[h], li = lam[NH + h];
    float hre = 0.0f, him = 0.0f;
    if (c == 0) { hre = state_re[b * NH + h]; him = state_im[b * NH + h]; }

    const bf16* bp = Bu + ((size_t)tstart * BATCH + b) * 512 + 2 * h;
    const size_t tstride = (size_t)BATCH * 512;   // elems per t step

    unsigned int vbuf[PF];
    #pragma unroll
    for (int p = 0; p < PF; ++p)
        vbuf[p] = *(const unsigned int*)(bp + p * tstride);   // PF <= 32 <= nIter

    char* sHB = (char*)sH;
    const int skip = nIter - SC;   // halo iterations before t0
    for (int base = 0; base < nIter; base += PF) {
        #pragma unroll
        for (int p = 0; p < PF; ++p) {
            int it = base + p;
            unsigned int v = vbuf[p];
            int tp = it + PF;
            if (tp < nIter)
                vbuf[p] = *(const unsigned int*)(bp + (size_t)tp * tstride);
            float bre = __uint_as_float(v << 16);
            float bim = __uint_as_float(v & 0xffff0000u);
            int st = (int)((mask >> it) & 1ull);
            float nr = st ? bre : fmaf(lr, hre, fmaf(-li, him, bre));
            float ni = st ? bim : fmaf(lr, him, fmaf(li, hre, bim));
            hre = nr; him = ni;
            int tl = it - skip;
            if (tl >= 0) {
                int a = tl * 2 + bi;                  // GEMM A-row
                int slot = (h >> 2) ^ (a & 7);        // 16B-slot XOR swizzle
                unsigned int packed =
                    ((unsigned int)f2bf_bits(him) << 16) | f2bf_bits(hre);
                *(unsigned int*)(sHB + a * 1024 + slot * 16 + (h & 3) * 4) = packed;
            }
        }
    }
    __syncthreads();   // sH published; sB(k0=0) drained (implicit vmcnt 0)

    // ---- Phase 2: GEMM 64x256, K=512; A from swizzled sH, B staged in sB ----
    const int wm   = w >> 2;            // rows wm*32..+32
    const int wn   = w & 3;             // cols wn*64..+64
    const int l15  = lane & 15;
    const int q    = lane >> 4;
    const int slotq = q ^ ((l15 >> 1) & 3);   // sB read slot (row-invariant)

    f32x4 acc[2][4];
    #pragma unroll
    for (int i = 0; i < 2; ++i)
        #pragma unroll
        for (int j = 0; j < 4; ++j) acc[i][j] = (f32x4){0.f, 0.f, 0.f, 0.f};

    for (int it = 0; it < 16; ++it) {
        const int k0 = it * 32;

        bf16x8 af[2], bfr[4];
        #pragma unroll
        for (int i = 0; i < 2; ++i) {
            int a = wm * 32 + i * 16 + l15;
            int slot = ((k0 >> 3) + q) ^ (a & 7);
            af[i] = *(const bf16x8*)(sHB + a * 1024 + slot * 16);
        }
        #pragma unroll
        for (int j = 0; j < 4; ++j)
            bfr[j] = *(const bf16x8*)&sB[(wn * 64 + j * 16 + l15) * 32 + slotq * 8];

        __syncthreads();   // all waves have read sB (own lgkm drained pre-bar)

        if (it < 15) {     // begin overwriting sB for k0+32; MFMA hides part
            async16(gBs + k0 + 32,            lBs);
            async16(gBs + 16 * 512 + k0 + 32, lBs + 16 * 32);
        }

        #pragma unroll
        for (int i = 0; i < 2; ++i)
            #pragma unroll
            for (int j = 0; j < 4; ++j)
                acc[i][j] = __builtin_amdgcn_mfma_f32_16x16x32_bf16(
                    af[i], bfr[j], acc[i][j], 0, 0, 0);

        if (it < 15) __syncthreads();   // stage(it+1) landed (implicit vmcnt 0)
    }

    // Epilogue: a = tl*2 + bi -> m = (t0+tl)*16 + b0 + bi, + D*x skip
    #pragma unroll
    for (int j = 0; j < 4; ++j) {
        int col = wn * 64 + j * 16 + l15;
        float dv = Dvec[col];
        #pragma unroll
        for (int i = 0; i < 2; ++i) {
            #pragma unroll
            for (int r = 0; r < 4; ++r) {
                int a = wm * 32 + i * 16 + q * 4 + r;
                size_t m = (size_t)(t0 + (a >> 1)) * BATCH + b0 + (a & 1);
                out[m * 256 + col] = acc[i][j][r] + dv * x[m * 256 + col];
            }
        }
    }
}

// ---------------------------------------------------------------------------
// Launch. Workspace: lam 2KB | WaT 256KB | WcT 256KB | Bu 64MB (~65MB total).
// cvt/xb eliminated: gemm_a reads f32 x directly (DMA-staged, cvt at
// fragment read). 3 kernels total.
// ---------------------------------------------------------------------------
extern "C" void kernel_launch(void* const* d_in, const int* in_sizes, int n_in,
                              void* d_out, int out_size, void* d_ws, size_t ws_size,
                              hipStream_t stream)
{
    const float* x         = (const float*)d_in[0];
    const int*   starts    = (const int*)d_in[1];
    const float* state_re  = (const float*)d_in[2];
    const float* state_im  = (const float*)d_in[3];
    const float* nu_log    = (const float*)d_in[4];
    const float* theta_log = (const float*)d_in[5];
    const float* B_re      = (const float*)d_in[6];
    const float* B_im      = (const float*)d_in[7];
    const float* C_re      = (const float*)d_in[8];
    const float* C_im      = (const float*)d_in[9];
    const float* Dvec      = (const float*)d_in[10];
    float* out = (float*)d_out;

    char* ws = (char*)d_ws;
    float* lam = (float*)ws;                            // 2*NH f32
    bf16*  WaT = (bf16*)(ws + 4096);                    // 512x256 bf16
    bf16*  WcT = (bf16*)(ws + 4096 + 512 * 256 * 2);    // 256x512 bf16
    bf16*  Bu  = (bf16*)(ws + (1 << 20));               // 65536x512 bf16 (64MB)

    // Prep weights + lam (block 1024): one launch.
    prep_w_kernel<<<1025, 256, 0, stream>>>(nu_log, theta_log,
                                            B_re, B_im, C_re, C_im,
                                            WaT, WcT, lam);

    // Stage A (cvt fused): Bu = bf16(x) @ WaT^T  (M=65536, K=256, N=512).
    gemm_a_kernel<<<2048, 256, 0, stream>>>(x, WaT, Bu);

    // Fused scan + stage C: 1024 blocks = (chunk, batch-pair), 512 threads.
    scan_gemmc_kernel<<<(T_LEN / SC) * (BATCH / 2), 512, 0, stream>>>(
        Bu, WcT, lam, starts, state_re, state_im, x, Dvec, out);
}